// Round 3
// baseline (114.067 us; speedup 1.0000x reference)
//
#include <hip/hip_runtime.h>

#define N_PIX   65536
#define N_GAUSS 2048
#define GCHUNK  256                      // Gaussians per block
#define NCHUNK  (N_GAUSS / GCHUNK)       // 8 chunks
#define NPIXBLK (N_PIX / 256)            // 256 pixel blocks
#define GSTRIDE 16                       // floats per Gaussian record (64 B aligned)

// Per-Gaussian record (16 floats, 64B): {A,B,C,D,E,F,r,g,b, pad...}
// q = A*px^2 + B*px*py + C*py^2 + D*px + E*py + F   (includes -0.5*log2(e))
// w = exp2(q) == exp(-0.5 * maha)
__global__ __launch_bounds__(256) void prep_kernel(
        const float* __restrict__ mus,
        const float* __restrict__ covs,
        const float* __restrict__ cols,
        float* __restrict__ gc) {
    int m = blockIdx.x * blockDim.x + threadIdx.x;
    if (m >= N_GAUSS) return;
    float c00 = covs[4*m+0], c01 = covs[4*m+1];
    float c10 = covs[4*m+2], c11 = covs[4*m+3];
    float inv_det = 1.0f / (c00*c11 - c01*c10);
    float ia =  c11 * inv_det;              // cov_inv[0][0]
    float ib = -c01 * inv_det;              // cov_inv[0][1] == [1][0]
    float ic =  c00 * inv_det;              // cov_inv[1][1]
    float mx = mus[2*m+0], my = mus[2*m+1];
    const float k = -0.7213475204444817f;   // -0.5 * log2(e)
    float A = k * ia;
    float B = k * 2.0f * ib;
    float C = k * ic;
    float D = -2.0f * k * (ia*mx + ib*my);
    float E = -2.0f * k * (ib*mx + ic*my);
    float F = k * (ia*mx*mx + 2.0f*ib*mx*my + ic*my*my);
    float* r = gc + m * GSTRIDE;
    r[0] = A; r[1] = B; r[2] = C; r[3] = D; r[4] = E; r[5] = F;
    r[6] = cols[3*m+0]; r[7] = cols[3*m+1]; r[8] = cols[3*m+2];
    r[9] = 0.f; r[10] = 0.f; r[11] = 0.f; r[12] = 0.f; r[13] = 0.f; r[14] = 0.f; r[15] = 0.f;
}

__global__ __launch_bounds__(256, 8) void render_kernel(
        const float2* __restrict__ x,
        const float* __restrict__ gc,
        float* __restrict__ out) {
    int pixblk = blockIdx.x % NPIXBLK;
    int chunk  = blockIdx.x / NPIXBLK;
    int t = threadIdx.x;

    int n = pixblk * 256 + t;
    float2 p = x[n];
    float px2  = p.x * p.x;
    float py2  = p.y * p.y;
    float pxpy = p.x * p.y;
    float accr = 0.f, accg = 0.f, accb = 0.f;

    // Wave-uniform address -> compiler emits s_load_dwordx16 per Gaussian;
    // every vector op below reads at most one SGPR operand.
    const float* g = gc + (size_t)chunk * GCHUNK * GSTRIDE;
    #pragma unroll 8
    for (int m = 0; m < GCHUNK; ++m) {
        const float* c = g + m * GSTRIDE;
        float q = fmaf(c[0], px2,
                  fmaf(c[1], pxpy,
                  fmaf(c[2], py2,
                  fmaf(c[3], p.x,
                  fmaf(c[4], p.y, c[5])))));
        float w = __builtin_amdgcn_exp2f(q);
        accr = fmaf(w, c[6], accr);
        accg = fmaf(w, c[7], accg);
        accb = fmaf(w, c[8], accb);
    }
    unsafeAtomicAdd(&out[3*n+0], accr);
    unsafeAtomicAdd(&out[3*n+1], accg);
    unsafeAtomicAdd(&out[3*n+2], accb);
}

extern "C" void kernel_launch(void* const* d_in, const int* in_sizes, int n_in,
                              void* d_out, int out_size, void* d_ws, size_t ws_size,
                              hipStream_t stream) {
    const float* x    = (const float*)d_in[0];   // [N_PIX, 2]
    const float* mus  = (const float*)d_in[1];   // [N_GAUSS, 2]
    const float* covs = (const float*)d_in[2];   // [N_GAUSS, 2, 2]
    const float* cols = (const float*)d_in[3];   // [N_GAUSS, 3]
    float* out = (float*)d_out;                  // [N_PIX, 3]
    float* gc  = (float*)d_ws;                   // 2048 * 64 B = 128 KB

    // chunks accumulate atomically -> zero the poisoned output first
    hipMemsetAsync(out, 0, (size_t)out_size * sizeof(float), stream);

    prep_kernel<<<(N_GAUSS + 255) / 256, 256, 0, stream>>>(mus, covs, cols, gc);
    render_kernel<<<NPIXBLK * NCHUNK, 256, 0, stream>>>((const float2*)x, gc, out);
}

// Round 7
// 84.312 us; speedup vs baseline: 1.3529x; 1.3529x over previous
//
#include <hip/hip_runtime.h>

#define N_PIX   65536
#define N_GAUSS 2048

typedef __bf16 bf16x8 __attribute__((ext_vector_type(8)));
typedef float  f32x4  __attribute__((ext_vector_type(4)));

union BF8U { uint4 u; bf16x8 h; };
__device__ inline bf16x8 as_bf(uint4 u) { BF8U x; x.u = u; return x.h; }

__device__ inline unsigned short bfbits(float f) {
  __bf16 h = (__bf16)f;
  return __builtin_bit_cast(unsigned short, h);
}
__device__ inline float bf2f(unsigned short b) {
  return (float)__builtin_bit_cast(__bf16, b);
}
__device__ inline unsigned pkb(unsigned short a, unsigned short b) {
  return (unsigned)a | ((unsigned)b << 16);
}
__device__ inline unsigned pk2f(float a, float b) {
  return pkb(bfbits(a), bfbits(b));
}

// ---------------------------------------------------------------------------
// K-layout (shared by P and G, K=32, 24 used):
//   k0-5 : Ghi*Phi   k6-11: Glo*Phi   k12-17: Ghi*Plo   k18-23: Glo*Plo
// so  q = sum_i (Ghi+Glo)_i * (Phi+Plo)_i  — full hi/lo split product,
// error ~2^-16 relative per term. Coefs include -0.5*log2(e) so w=exp2(q).
//
// ws layout: [0, 8192)   uint4 : GQ frags, 128 tiles x 64 lanes x 16B (A-op)
//            [8192,12288) uint4 : PVC frags, 64 tiles x 64 lanes x 16B (B-op)
// ---------------------------------------------------------------------------

__global__ __launch_bounds__(256) void prep_kernel(
    const float* __restrict__ mus, const float* __restrict__ covs,
    const float* __restrict__ cols, uint4* __restrict__ ws) {
  int tid = blockIdx.x * 256 + threadIdx.x;
  if (tid < 8192) {
    // GQ fragment: A-operand of q-MFMA. lane row = gauss (lane&15),
    // k = (lane>>4)*8 + j.  G row = [Chi0-5, Clo0-5, Chi0-5, Clo0-5, 0...]
    int lane = tid & 63;
    int tile = tid >> 6;
    int grp  = lane >> 4;
    int g    = tile * 16 + (lane & 15);
    float c00 = covs[4*g+0], c01 = covs[4*g+1];
    float c10 = covs[4*g+2], c11 = covs[4*g+3];
    float inv_det = 1.0f / (c00*c11 - c01*c10);
    float ia =  c11 * inv_det;
    float ib = -c01 * inv_det;
    float ic =  c00 * inv_det;
    float mx = mus[2*g+0], my = mus[2*g+1];
    const float kk = -0.7213475204444817f;   // -0.5*log2(e)
    float coef[6];
    coef[0] = kk * ia;
    coef[1] = kk * 2.0f * ib;
    coef[2] = kk * ic;
    coef[3] = -2.0f * kk * (ia*mx + ib*my);
    coef[4] = -2.0f * kk * (ib*mx + ic*my);
    coef[5] = kk * (ia*mx*mx + 2.0f*ib*mx*my + ic*my*my);
    unsigned short ch[6], cl[6];
    #pragma unroll
    for (int i = 0; i < 6; ++i) {
      ch[i] = bfbits(coef[i]);
      cl[i] = bfbits(coef[i] - bf2f(ch[i]));
    }
    uint4 v = make_uint4(0,0,0,0);
    if (grp == 0)      v = make_uint4(pkb(ch[0],ch[1]), pkb(ch[2],ch[3]), pkb(ch[4],ch[5]), pkb(cl[0],cl[1]));
    else if (grp == 1) v = make_uint4(pkb(cl[2],cl[3]), pkb(cl[4],cl[5]), pkb(ch[0],ch[1]), pkb(ch[2],ch[3]));
    else if (grp == 2) v = make_uint4(pkb(ch[4],ch[5]), pkb(cl[0],cl[1]), pkb(cl[2],cl[3]), pkb(cl[4],cl[5]));
    ws[tid] = v;
  } else if (tid < 12288) {
    // PVC fragment: B-operand of PV MFMA (K=32 gauss, N=16 rgb, 3 used).
    // lane col = rgb (lane&15), k = (lane>>4)*8 + j.
    int t2   = tid - 8192;
    int lane = t2 & 63;
    int tile = t2 >> 6;
    int rgb  = lane & 15;
    int kb   = (lane >> 4) * 8;
    uint4 v = make_uint4(0,0,0,0);
    if (rgb < 3) {
      unsigned short b[8];
      #pragma unroll
      for (int j = 0; j < 8; ++j)
        b[j] = bfbits(cols[(tile*32 + kb + j)*3 + rgb]);
      v = make_uint4(pkb(b[0],b[1]), pkb(b[2],b[3]), pkb(b[4],b[5]), pkb(b[6],b[7]));
    }
    ws[8192 + t2] = v;
  }
}

// ---------------------------------------------------------------------------
// Render: 512 threads (8 waves) per block, 16 pixels per wave, 128 per block.
// Per chunk of 256 gaussians: stage GQ (16KB) + PVC (8KB) into LDS; per
// 32-gauss pair: 2 swapped q-MFMAs -> exp2 -> bf16 pack -> wave-private W
// buffer in LDS (swizzled) -> PV MFMA accumulate. Output written once, no
// atomics.
// LDS map (uint4 idx): [0,1024) GQ, [1024,1536) PVC, [1536,2048) W (8x1KB).
// ---------------------------------------------------------------------------
__global__ __launch_bounds__(512, 4) void render_kernel(
    const float2* __restrict__ x, const uint4* __restrict__ ws,
    float* __restrict__ out) {
  __shared__ uint4 smem[2048];                  // 32 KB
  const uint4* gq  = ws;                        // 8192 uint4
  const uint4* pvc = ws + 8192;                 // 4096 uint4

  int tid  = threadIdx.x;
  int lane = tid & 63, wave = tid >> 6;
  int c    = lane & 15, grp = lane >> 4;
  int wpix = blockIdx.x * 128 + wave * 16;

  // P fragment: B-operand of q-MFMA. lane col = pix (lane&15),
  // k = grp*8 + j.  P col = [Phi0-5, Phi0-5, Plo0-5, Plo0-5, 0...]
  float2 p = x[wpix + c];
  float mono[6] = {p.x*p.x, p.x*p.y, p.y*p.y, p.x, p.y, 1.0f};
  unsigned short ph[6], pl[6];
  #pragma unroll
  for (int i = 0; i < 6; ++i) {
    ph[i] = bfbits(mono[i]);
    pl[i] = bfbits(mono[i] - bf2f(ph[i]));
  }
  uint4 pv4 = make_uint4(0,0,0,0);
  if (grp == 0)      pv4 = make_uint4(pkb(ph[0],ph[1]), pkb(ph[2],ph[3]), pkb(ph[4],ph[5]), pkb(ph[0],ph[1]));
  else if (grp == 1) pv4 = make_uint4(pkb(ph[2],ph[3]), pkb(ph[4],ph[5]), pkb(pl[0],pl[1]), pkb(pl[2],pl[3]));
  else if (grp == 2) pv4 = make_uint4(pkb(pl[4],pl[5]), pkb(pl[0],pl[1]), pkb(pl[2],pl[3]), pkb(pl[4],pl[5]));
  bf16x8 pf = as_bf(pv4);

  // Wave-private W buffer: [pix 16][gauss 32] bf16 (1KB), XOR-swizzled so
  // both the b64 writes and b128 reads sit at the bank floor.
  char* Wb = (char*)smem + 24576 + (wave << 10);
  int b0 = c*64 + grp*8;          // write, q-tile parity 0 (gauss 4*grp+0..3)
  int b1 = c*64 + 32 + grp*8;     // write, parity 1
  int br = c*64 + grp*16;         // read: pix=c, gauss 8*grp..+7
  uint2* wp0 = (uint2*)(Wb + (b0 ^ (((b0 >> 7) & 3) << 4)));
  uint2* wp1 = (uint2*)(Wb + (b1 ^ (((b1 >> 7) & 3) << 4)));
  const uint4* rp = (const uint4*)(Wb + (br ^ (((br >> 7) & 3) << 4)));

  f32x4 acc  = {0.f, 0.f, 0.f, 0.f};
  const f32x4 zero = {0.f, 0.f, 0.f, 0.f};

  // Software-pipelined staging: loads for chunk k+1 issue before compute(k).
  uint4 s0 = gq[tid], s1 = gq[512 + tid], s2 = pvc[tid];
  for (int chk = 0; chk < 8; ++chk) {
    __syncthreads();                       // all waves done reading prev chunk
    smem[tid] = s0; smem[512 + tid] = s1; smem[1024 + tid] = s2;
    __syncthreads();
    if (chk < 7) {
      s0 = gq[(chk+1)*1024 + tid];
      s1 = gq[(chk+1)*1024 + 512 + tid];
      s2 = pvc[(chk+1)*512 + tid];
    }
    #pragma unroll
    for (int pr = 0; pr < 8; ++pr) {       // 8 x 32 gaussians
      uint4 ga = smem[(2*pr+0)*64 + lane];
      uint4 gb = smem[(2*pr+1)*64 + lane];
      // swapped QK^T: D[gauss][pix] (row=gauss=grp*4+reg, col=pix=c)
      f32x4 q0 = __builtin_amdgcn_mfma_f32_16x16x32_bf16(as_bf(ga), pf, zero, 0, 0, 0);
      f32x4 q1 = __builtin_amdgcn_mfma_f32_16x16x32_bf16(as_bf(gb), pf, zero, 0, 0, 0);
      uint2 w0, w1;
      w0.x = pk2f(__builtin_amdgcn_exp2f(q0[0]), __builtin_amdgcn_exp2f(q0[1]));
      w0.y = pk2f(__builtin_amdgcn_exp2f(q0[2]), __builtin_amdgcn_exp2f(q0[3]));
      w1.x = pk2f(__builtin_amdgcn_exp2f(q1[0]), __builtin_amdgcn_exp2f(q1[1]));
      w1.y = pk2f(__builtin_amdgcn_exp2f(q1[2]), __builtin_amdgcn_exp2f(q1[3]));
      *wp0 = w0;                           // W[pix=c][gauss 4g+0..3]
      *wp1 = w1;                           // W[pix=c][16 + 4g+0..3]
      asm volatile("s_waitcnt lgkmcnt(0)" ::: "memory");
      uint4 wf = *rp;                      // A-op: w[pix=c][gauss 8*grp..+7]
      uint4 cf = smem[1024 + pr*64 + lane];
      // PV: D[pix][rgb] += w * colsT  (row=pix=grp*4+reg, col=rgb=c)
      acc = __builtin_amdgcn_mfma_f32_16x16x32_bf16(as_bf(wf), as_bf(cf), acc, 0, 0, 0);
    }
  }
  if (c < 3) {
    int pix = wpix + grp * 4;
    out[(pix+0)*3 + c] = acc[0];
    out[(pix+1)*3 + c] = acc[1];
    out[(pix+2)*3 + c] = acc[2];
    out[(pix+3)*3 + c] = acc[3];
  }
}

extern "C" void kernel_launch(void* const* d_in, const int* in_sizes, int n_in,
                              void* d_out, int out_size, void* d_ws, size_t ws_size,
                              hipStream_t stream) {
  const float* x    = (const float*)d_in[0];   // [N_PIX, 2]
  const float* mus  = (const float*)d_in[1];   // [N_GAUSS, 2]
  const float* covs = (const float*)d_in[2];   // [N_GAUSS, 2, 2]
  const float* cols = (const float*)d_in[3];   // [N_GAUSS, 3]
  float* out = (float*)d_out;                  // [N_PIX, 3]
  uint4* ws  = (uint4*)d_ws;                   // 192 KB of fragments

  prep_kernel<<<48, 256, 0, stream>>>(mus, covs, cols, ws);
  render_kernel<<<512, 512, 0, stream>>>((const float2*)x, ws, out);
}